// Round 4
// baseline (20.459 us; speedup 1.0000x reference)
//
#include <hip/hip_runtime.h>

__device__ __forceinline__ float frcp(float x){ return __builtin_amdgcn_rcpf(x); }

// Clip P's 4 edges against Q's 4 half-planes using a precomputed s-table
// (s[p][k] = scaled signed distance of P corner p to Q plane k, >=0 inside).
// Returns sum of cross(start,end) over kept sub-segments (order-free Green sum).
__device__ __forceinline__ float clip_half(const float px[4], const float py[4],
                                           const float s[4][4])
{
    float acc = 0.f;
    #pragma unroll
    for (int e = 0; e < 4; e++) {
        const int en = (e+1)&3;
        float t0 = 0.f, t1 = 1.f;
        bool empty = false;
        #pragma unroll
        for (int k = 0; k < 4; k++) {
            float sa = s[e][k], sb = s[en][k];
            bool ain = sa >= 0.f, bin = sb >= 0.f;
            float ts = sa * frcp(sa - sb);   // only consumed when signs differ
            t1 = (ain && !bin) ? fminf(t1, ts) : t1;
            t0 = (!ain && bin) ? fmaxf(t0, ts) : t0;
            empty = empty || (!ain && !bin);
        }
        bool valid = (!empty) && (t1 > t0);
        float axv = px[e], ayv = py[e];
        float dx = px[en] - axv, dy = py[en] - ayv;
        float pax = fmaf(t0, dx, axv), pay = fmaf(t0, dy, ayv);
        float pbx = fmaf(t1, dx, axv), pby = fmaf(t1, dy, ayv);
        acc += valid ? (pax*pby - pay*pbx) : 0.f;
    }
    return acc;
}

__device__ __forceinline__ float box_pair_loss(
    const float* __restrict__ pred, const float* __restrict__ target, int i)
{
    const float p0 = pred[5*i+0], p1 = pred[5*i+1], p2 = pred[5*i+2], p3 = pred[5*i+3], p4 = pred[5*i+4];
    const float q0 = target[5*i+0], q1 = target[5*i+1], q2 = target[5*i+2], q3 = target[5*i+3], q4 = target[5*i+4];

    // common center for f32 cancellation
    const float cx = 0.5f*(p0 + q0), cy = 0.5f*(p1 + q1);
    const float oax = p0 - cx, oay = p1 - cy;
    const float obx = q0 - cx, oby = q1 - cy;

    const float cs1 = __cosf(p4), sn1 = __sinf(p4);
    const float cs2 = __cosf(q4), sn2 = __sinf(q4);

    // ---- corners (centered), CCW ----
    float ax[4], ay[4], bx[4], by[4];
    {
        const float DX[4] = {0.5f,-0.5f,-0.5f,0.5f};
        const float DY[4] = {0.5f, 0.5f,-0.5f,-0.5f};
        #pragma unroll
        for (int k = 0; k < 4; k++) {
            float dx = DX[k]*p2, dy = DY[k]*p3;
            ax[k] = dx*cs1 - dy*sn1 + oax;
            ay[k] = dx*sn1 + dy*cs1 + oay;
        }
        #pragma unroll
        for (int k = 0; k < 4; k++) {
            float dx = DX[k]*q2, dy = DY[k]*q3;
            bx[k] = dx*cs2 - dy*sn2 + obx;
            by[k] = dx*sn2 + dy*cs2 + oby;
        }
    }

    // ---- intersection area: order-free Green sum, s-tables reused ----
    float twoA;
    {
        float s[4][4];
        // A corners vs B planes
        #pragma unroll
        for (int k = 0; k < 4; k++) {
            float ex = bx[(k+1)&3] - bx[k], ey = by[(k+1)&3] - by[k];
            float qxk = bx[k], qyk = by[k];
            #pragma unroll
            for (int p = 0; p < 4; p++)
                s[p][k] = ex*(ay[p]-qyk) - ey*(ax[p]-qxk);
        }
        twoA = clip_half(ax, ay, s);
        // B corners vs A planes
        #pragma unroll
        for (int k = 0; k < 4; k++) {
            float ex = ax[(k+1)&3] - ax[k], ey = ay[(k+1)&3] - ay[k];
            float qxk = ax[k], qyk = ay[k];
            #pragma unroll
            for (int p = 0; p < 4; p++)
                s[p][k] = ex*(by[p]-qyk) - ey*(bx[p]-qxk);
        }
        twoA += clip_half(bx, by, s);
    }
    float inter_area = 0.5f * fabsf(twoA);

    // ---- union / iou ----
    float unionv = p2*p3 + q2*q3 - inter_area;
    float iou = fmaxf(inter_area * frcp(unionv), 1e-6f);

    // ---- smallest enclosing rect, closed form over the 2 distinct dirs ----
    float cD = cs1*cs2 + sn1*sn2;
    float sD = sn2*cs1 - cs2*sn1;
    float acd = fabsf(cD), asd = fabsf(sD);

    // direction = box1 axes
    float pAu = oax*cs1 + oay*sn1, pAv = -oax*sn1 + oay*cs1;
    float pBu = obx*cs1 + oby*sn1, pBv = -obx*sn1 + oby*cs1;
    float eAx = 0.5f*p2, eAy = 0.5f*p3;
    float eBx = 0.5f*(q2*acd + q3*asd), eBy = 0.5f*(q2*asd + q3*acd);
    float w1 = fmaxf(pAu+eAx, pBu+eBx) - fminf(pAu-eAx, pBu-eBx);
    float h1 = fmaxf(pAv+eAy, pBv+eBy) - fminf(pAv-eAy, pBv-eBy);
    float a1 = w1*h1;

    // direction = box2 axes
    float pAu2 = oax*cs2 + oay*sn2, pAv2 = -oax*sn2 + oay*cs2;
    float pBu2 = obx*cs2 + oby*sn2, pBv2 = -obx*sn2 + oby*cs2;
    float eB2x = 0.5f*q2, eB2y = 0.5f*q3;
    float eA2x = 0.5f*(p2*acd + p3*asd), eA2y = 0.5f*(p2*asd + p3*acd);
    float w2 = fmaxf(pAu2+eA2x, pBu2+eB2x) - fminf(pAu2-eA2x, pBu2-eB2x);
    float h2 = fmaxf(pAv2+eA2y, pBv2+eB2y) - fminf(pAv2-eA2y, pBv2-eB2y);
    float a2 = w2*h2;

    float area_c = (a2 < a1) ? a2 : a1;   // box1 dirs first in ref argmin

    float r = (area_c - unionv) * frcp(area_c);
    float giou = iou*iou*iou - r*r*r;
    return 1.0f - giou;
}

__global__ __launch_bounds__(256) void giou_partial_kernel(
    const float* __restrict__ pred, const float* __restrict__ target,
    float* __restrict__ partial, int n, int half)
{
    int t = blockIdx.x * blockDim.x + threadIdx.x;
    // two independent box pairs per thread -> ILP to hide dependency latency
    float loss = 0.0f;
    if (t < half)     loss  = box_pair_loss(pred, target, t);
    int t2 = t + half;
    if (t2 < n && t < half) loss += box_pair_loss(pred, target, t2);

    // ---- deterministic block reduction ----
    #pragma unroll
    for (int off = 32; off; off >>= 1) loss += __shfl_down(loss, off, 64);
    __shared__ float smem[4];
    int lane = threadIdx.x & 63, wid = threadIdx.x >> 6;
    if (lane == 0) smem[wid] = loss;
    __syncthreads();
    if (threadIdx.x == 0) {
        partial[blockIdx.x] = smem[0] + smem[1] + smem[2] + smem[3];
    }
}

__global__ __launch_bounds__(256) void reduce_final_kernel(
    const float* __restrict__ partial, int nb, float* __restrict__ out, float invn)
{
    float s = 0.f;
    for (int i = threadIdx.x; i < nb; i += 256) s += partial[i];
    #pragma unroll
    for (int off = 32; off; off >>= 1) s += __shfl_down(s, off, 64);
    __shared__ float smem[4];
    int lane = threadIdx.x & 63, wid = threadIdx.x >> 6;
    if (lane == 0) smem[wid] = s;
    __syncthreads();
    if (threadIdx.x == 0) {
        out[0] = (smem[0] + smem[1] + smem[2] + smem[3]) * invn;
    }
}

extern "C" void kernel_launch(void* const* d_in, const int* in_sizes, int n_in,
                              void* d_out, int out_size, void* d_ws, size_t ws_size,
                              hipStream_t stream) {
    const float* pred   = (const float*)d_in[0];
    const float* target = (const float*)d_in[1];
    float* out = (float*)d_out;
    float* partial = (float*)d_ws;
    int n    = in_sizes[0] / 5;
    int half = (n + 1) / 2;                 // thread t handles t and t+half
    int nb   = (half + 255) / 256;
    giou_partial_kernel<<<nb, 256, 0, stream>>>(pred, target, partial, n, half);
    reduce_final_kernel<<<1, 256, 0, stream>>>(partial, nb, out, 1.0f/(float)n);
}